// Round 11
// baseline (445.938 us; speedup 1.0000x reference)
//
#include <hip/hip_runtime.h>
#include <cstdint>
#include <cstddef>

#define D_DIM 256
#define NT 64            // codes per sweep tile
#define SROWS 256        // rows per sweep block
#define SNS 4            // K splits in sweep (grid = 128*4 = 512)
#define MARGIN 7.0e-4f   // worst-case-safe approx-dot margin (see analysis)

typedef unsigned int u32;
typedef unsigned short u16;
typedef __attribute__((ext_vector_type(8))) short s16x8;
typedef __attribute__((ext_vector_type(4))) float f32x4;

static __device__ __forceinline__ u16 f2bf(float f) {
  u32 u = __float_as_uint(f);
  return (u16)((u + 0x7FFFu + ((u >> 16) & 1u)) >> 16);
}

// numpy pairwise_sum block for n=128 (bit-identical to rounds 6-10)
static __device__ __forceinline__ float np_pw128_sq(const float* __restrict__ p) {
  float r0, r1, r2, r3, r4, r5, r6, r7;
  {
    const float4 a = *reinterpret_cast<const float4*>(p);
    const float4 b = *reinterpret_cast<const float4*>(p + 4);
    r0 = __fmul_rn(a.x, a.x); r1 = __fmul_rn(a.y, a.y);
    r2 = __fmul_rn(a.z, a.z); r3 = __fmul_rn(a.w, a.w);
    r4 = __fmul_rn(b.x, b.x); r5 = __fmul_rn(b.y, b.y);
    r6 = __fmul_rn(b.z, b.z); r7 = __fmul_rn(b.w, b.w);
  }
  #pragma unroll
  for (int i = 8; i < 128; i += 8) {
    const float4 a = *reinterpret_cast<const float4*>(p + i);
    const float4 b = *reinterpret_cast<const float4*>(p + i + 4);
    r0 = __fadd_rn(r0, __fmul_rn(a.x, a.x));
    r1 = __fadd_rn(r1, __fmul_rn(a.y, a.y));
    r2 = __fadd_rn(r2, __fmul_rn(a.z, a.z));
    r3 = __fadd_rn(r3, __fmul_rn(a.w, a.w));
    r4 = __fadd_rn(r4, __fmul_rn(b.x, b.x));
    r5 = __fadd_rn(r5, __fmul_rn(b.y, b.y));
    r6 = __fadd_rn(r6, __fmul_rn(b.z, b.z));
    r7 = __fadd_rn(r7, __fmul_rn(b.w, b.w));
  }
  const float s01 = __fadd_rn(r0, r1);
  const float s23 = __fadd_rn(r2, r3);
  const float s45 = __fadd_rn(r4, r5);
  const float s67 = __fadd_rn(r6, r7);
  return __fadd_rn(__fadd_rn(s01, s23), __fadd_rn(s45, s67));
}

// ---- K0: f32 -> bf16 stash (r10 verbatim) ----
__global__ __launch_bounds__(256) void cvt_kernel(
    const float* __restrict__ X, const float* __restrict__ W,
    u16* __restrict__ Xb, u16* __restrict__ Wb, int nx4, int nw4) {
  const int tid = blockIdx.x * blockDim.x + threadIdx.x;
  const int stride = gridDim.x * blockDim.x;
  for (int g = tid; g < nx4; g += stride) {
    const float4 v = reinterpret_cast<const float4*>(X)[g];
    ushort4 o; o.x = f2bf(v.x); o.y = f2bf(v.y); o.z = f2bf(v.z); o.w = f2bf(v.w);
    reinterpret_cast<ushort4*>(Xb)[g] = o;
  }
  for (int g = tid; g < nw4; g += stride) {
    const float4 v = reinterpret_cast<const float4*>(W)[g];
    ushort4 o; o.x = f2bf(v.x); o.y = f2bf(v.y); o.z = f2bf(v.z); o.w = f2bf(v.w);
    reinterpret_cast<ushort4*>(Wb)[g] = o;
  }
}

// 16-lane (DPP row) max-reduce of (v, idx), ties -> lower idx. VALU-only.
#define DPP_RED_STEP(CTRL)                                                     \
  {                                                                            \
    const float ov = __uint_as_float((u32)__builtin_amdgcn_update_dpp(         \
        0, (int)__float_as_uint(v), CTRL, 0xF, 0xF, true));                    \
    const int oi = __builtin_amdgcn_update_dpp(0, idx, CTRL, 0xF, 0xF, true);  \
    if (ov > v || (ov == v && oi < idx)) { v = ov; idx = oi; }                 \
  }

// ---- K1: MFMA sweep -> per-(row, 64-code-tile) top-1 (value f32 + idx u16)
// grid = (N/SROWS)*SNS = 512, block 256 (4 waves x 64 rows, rt=4)
__global__ __launch_bounds__(256, 2) void vq_sweep(
    const u16* __restrict__ Xb, const u16* __restrict__ Wb,
    float* __restrict__ tm, u16* __restrict__ ti, int K) {
  __shared__ u16 Ws[NT * D_DIM];  // 32 KB, [kc8][code][8] subtiled (r10 layout)

  const int t = threadIdx.x;
  const int wv = t >> 6;
  const int lane = t & 63;
  const int l15 = lane & 15, lhi = lane >> 4;
  const int rb = blockIdx.x >> 2;      // SNS == 4
  const int hs = blockIdx.x & 3;
  const int row0 = rb * SROWS;
  const int wrow0 = row0 + wv * 64;
  const int c00 = hs * (K / SNS);      // 1024 codes per split

  // A fragments: wave's 64 rows x 256 d in registers (128 VGPR)
  s16x8 af[4][8];
  #pragma unroll
  for (int rt = 0; rt < 4; ++rt)
    #pragma unroll
    for (int kc = 0; kc < 8; ++kc)
      af[rt][kc] = *reinterpret_cast<const s16x8*>(
          Xb + (size_t)(wrow0 + rt * 16 + l15) * D_DIM + kc * 32 + lhi * 8);

  const int NTILES = K / SNS / NT;  // 16
  for (int ct = 0; ct < NTILES; ++ct) {
    __syncthreads();
    {  // stage W tile (r10-verbatim layout): codes c00+ct*64 .. +63
      const int code = t >> 2, k4 = t & 3;
      const u16* wp = Wb + (size_t)(c00 + ct * NT + code) * D_DIM;
      #pragma unroll
      for (int kk = 0; kk < 8; ++kk) {
        const int kc8 = kk * 4 + k4;
        *reinterpret_cast<uint4*>(&Ws[(kc8 * NT + code) * 8]) =
            *reinterpret_cast<const uint4*>(wp + kc8 * 8);
      }
    }
    __syncthreads();

    f32x4 acc[4][4];
    #pragma unroll
    for (int rt = 0; rt < 4; ++rt)
      #pragma unroll
      for (int c = 0; c < 4; ++c) acc[rt][c] = f32x4{0.f, 0.f, 0.f, 0.f};

    #pragma unroll
    for (int kc = 0; kc < 8; ++kc) {
      s16x8 bf[4];
      #pragma unroll
      for (int c = 0; c < 4; ++c)
        bf[c] = *reinterpret_cast<const s16x8*>(
            &Ws[((kc * 4 + lhi) * NT + c * 16 + l15) * 8]);
      #pragma unroll
      for (int c = 0; c < 4; ++c) {
        acc[0][c] = __builtin_amdgcn_mfma_f32_16x16x32_bf16(af[0][kc], bf[c], acc[0][c], 0, 0, 0);
        acc[1][c] = __builtin_amdgcn_mfma_f32_16x16x32_bf16(af[1][kc], bf[c], acc[1][c], 0, 0, 0);
        acc[2][c] = __builtin_amdgcn_mfma_f32_16x16x32_bf16(af[2][kc], bf[c], acc[2][c], 0, 0, 0);
        acc[3][c] = __builtin_amdgcn_mfma_f32_16x16x32_bf16(af[3][kc], bf[c], acc[3][c], 0, 0, 0);
      }
    }

    // per-row tile-top1 (value, idx): c-reduce in regs, 16-lane reduce via DPP
    #pragma unroll
    for (int rt = 0; rt < 4; ++rt)
      #pragma unroll
      for (int r = 0; r < 4; ++r) {
        float v = acc[rt][0][r];
        int idx = c00 + ct * NT + l15;               // c = 0, cols ascending
        #pragma unroll
        for (int c = 1; c < 4; ++c) {
          const float vc = acc[rt][c][r];
          const int ic = c00 + ct * NT + c * 16 + l15;
          if (vc > v) { v = vc; idx = ic; }          // strict > keeps lower col
        }
        DPP_RED_STEP(0x121)  // row_ror:1
        DPP_RED_STEP(0x122)  // row_ror:2
        DPP_RED_STEP(0x124)  // row_ror:4
        DPP_RED_STEP(0x128)  // row_ror:8
        if (l15 == 0) {
          const int row = wrow0 + rt * 16 + lhi * 4 + r;  // C/D map (r10-verified)
          const int tile = hs * NTILES + ct;
          tm[(size_t)row * 64 + tile] = v;
          ti[(size_t)row * 64 + tile] = (u16)idx;
        }
      }
  }
}

// ---- K2: resolve -> exact ref-chain on stored top-1s within margin ----
// grid = N/128 = 256, block 256
__global__ __launch_bounds__(256) void vq_resolve(
    const float* __restrict__ X, const float* __restrict__ W,
    const float* __restrict__ tm, const u16* __restrict__ ti,
    float* __restrict__ outI, int K) {
  __shared__ float ftmp[256];
  __shared__ float xsqs[128];
  const int t = threadIdx.x;
  const int row0 = blockIdx.x * 128;

  {  // per-row ||x||^2, numpy-pairwise-f32 exact
    const int r = t >> 1, half = t & 1;
    ftmp[t] = np_pw128_sq(X + (size_t)(row0 + r) * D_DIM + half * 128);
  }
  __syncthreads();
  if (t < 128) xsqs[t] = __fadd_rn(ftmp[2 * t], ftmp[2 * t + 1]);
  __syncthreads();

  if (t < 128) {
    const int row = row0 + t;
    const float* tmr = tm + (size_t)row * 64;
    const u16* tir = ti + (size_t)row * 64;

    float rowmax = -3.4e38f;
    #pragma unroll 8
    for (int i = 0; i < 64; ++i) rowmax = fmaxf(rowmax, tmr[i]);
    const float thr = rowmax - MARGIN;

    const float xsq = xsqs[t];
    const float* xp = X + (size_t)row * D_DIM;
    u32 bd = 0xFFFFFFFFu;
    int bi = 0;
    for (int i = 0; i < 64; ++i) {
      if (tmr[i] >= thr) {
        const int code = (int)tir[i] & (K - 1);
        const float* wp = W + (size_t)code * D_DIM;
        float a = 0.f;                         // exact r6-r10 chain
        #pragma unroll 8
        for (int d4 = 0; d4 < 64; ++d4) {
          const float4 xv = *reinterpret_cast<const float4*>(xp + d4 * 4);
          const float4 wv = *reinterpret_cast<const float4*>(wp + d4 * 4);
          a = fmaf(xv.x, wv.x, a);
          a = fmaf(xv.y, wv.y, a);
          a = fmaf(xv.z, wv.z, a);
          a = fmaf(xv.w, wv.w, a);
        }
        const float dist = __fsub_rn(xsq, 2.0f * a);   // always > 0 here
        const u32 db = __float_as_uint(dist);
        if (db < bd || (db == bd && code < bi)) { bd = db; bi = code; }
      }
    }
    outI[row] = (float)bi;
  }
}

// ---- K3: gather W[k], qst, commit partials (r10 verbatim) ----
__global__ __launch_bounds__(256) void vq_gather(
    const float* __restrict__ X, const float* __restrict__ W,
    const float* __restrict__ outI, float* __restrict__ outQ,
    double* __restrict__ partials, int K) {
  __shared__ double dsum[256];
  const int t = threadIdx.x;
  const int r = t >> 1, half = t & 1;
  const int row = blockIdx.x * 128 + r;
  const int ix = (int)outI[row];

  double csum = 0.0;
  {
    const int k = ix & (K - 1);
    const float* xp = X + (size_t)row * D_DIM + half * 128;
    const float* wp = W + (size_t)k * D_DIM + half * 128;
    float* op = outQ + (size_t)row * D_DIM + half * 128;
    #pragma unroll 4
    for (int i = 0; i < 128; i += 4) {
      const float4 xv = *reinterpret_cast<const float4*>(xp + i);
      const float4 wv = *reinterpret_cast<const float4*>(wp + i);
      const float d0 = __fsub_rn(wv.x, xv.x), d1 = __fsub_rn(wv.y, xv.y);
      const float d2 = __fsub_rn(wv.z, xv.z), d3 = __fsub_rn(wv.w, xv.w);
      csum += (double)d0 * d0 + (double)d1 * d1 + (double)d2 * d2 + (double)d3 * d3;
      float4 o;
      o.x = __fadd_rn(xv.x, d0);
      o.y = __fadd_rn(xv.y, d1);
      o.z = __fadd_rn(xv.z, d2);
      o.w = __fadd_rn(xv.w, d3);
      *reinterpret_cast<float4*>(op + i) = o;
    }
  }
  dsum[t] = csum;
  __syncthreads();
  for (int s = 128; s > 0; s >>= 1) {
    if (t < s) dsum[t] += dsum[t + s];
    __syncthreads();
  }
  if (t == 0) partials[blockIdx.x] = dsum[0];
}

// ---- K4: finalize scalars ----
__global__ __launch_bounds__(256) void vq_finalize(
    const double* __restrict__ partials, float* __restrict__ outS,
    double invCount) {
  __shared__ double dsum[256];
  const int t = threadIdx.x;
  dsum[t] = partials[t];
  __syncthreads();
  for (int s = 128; s > 0; s >>= 1) {
    if (t < s) dsum[t] += dsum[t + s];
    __syncthreads();
  }
  if (t == 0) {
    const float m = (float)(dsum[0] * invCount);
    outS[0] = __fadd_rn(m, __fmul_rn(0.25f, m));  // (1+BETA)*mean
    outS[1] = 0.f;
  }
}

// ---- host-anomaly beacons ----
__global__ void zero_out_kernel(float* __restrict__ out, int n) {
  const int i = blockIdx.x * blockDim.x + threadIdx.x;
  const int stride = gridDim.x * blockDim.x;
  for (int j = i; j < n; j += stride) out[j] = 0.f;
}
__global__ void beacon_kernel(float* __restrict__ out, float v) {
  if (threadIdx.x == 0) out[0] = v;
}

extern "C" void kernel_launch(void* const* d_in, const int* in_sizes, int n_in,
                              void* d_out, int out_size, void* d_ws, size_t ws_size,
                              hipStream_t stream) {
  float* outF = (float*)d_out;

  float hostBeacon = 0.f;
  if (n_in != 2) hostBeacon = 21.f;
  else if (in_sizes[0] != 32768 * 256) hostBeacon = 23.f;
  else if (in_sizes[1] != 4096 * 256) hostBeacon = 25.f;
  else if (ws_size < 4096) hostBeacon = 27.f;
  else if (out_size != 32768 * 256 + 32768 + 2) hostBeacon = 29.f;

  if (hostBeacon != 0.f) {
    zero_out_kernel<<<dim3(2048), dim3(256), 0, stream>>>(outF, out_size);
    beacon_kernel<<<dim3(1), dim3(64), 0, stream>>>(outF, hostBeacon);
    return;
  }

  const float* X = (const float*)d_in[0];   // f32 [32768, 256]
  const float* W = (const float*)d_in[1];   // f32 [4096, 256]
  const int N = 32768, K = 4096;

  double* partials = (double*)d_ws;          // 256 doubles = 2048 B
  float* outQ = outF;                        // [N*256]  (32 MiB)
  float* outI = outQ + (size_t)N * D_DIM;    // [N]
  float* outS = outI + N;                    // [2]

  // stash layout inside outQ (overwritten later by vq_gather):
  //   Xb bf16 [0, 16Mi) | Wb bf16 [16Mi, 18Mi) | tm f32 [18Mi, 26Mi) |
  //   ti u16 [26Mi, 30Mi)
  u16* Xb = (u16*)outQ;
  u16* Wb = (u16*)((char*)d_out + 16777216);
  float* tmv = (float*)((char*)d_out + 18874368);
  u16* tiv = (u16*)((char*)d_out + 27262976);

  cvt_kernel<<<dim3(2048), dim3(256), 0, stream>>>(
      X, W, Xb, Wb, N * D_DIM / 4, K * D_DIM / 4);
  vq_sweep<<<dim3((N / SROWS) * SNS), dim3(256), 0, stream>>>(Xb, Wb, tmv, tiv, K);
  vq_resolve<<<dim3(N / 128), dim3(256), 0, stream>>>(X, W, tmv, tiv, outI, K);
  vq_gather<<<dim3(N / 128), dim3(256), 0, stream>>>(X, W, outI, outQ, partials, K);
  vq_finalize<<<dim3(1), dim3(256), 0, stream>>>(partials, outS,
                                                 1.0 / ((double)N * D_DIM));
}

// Round 12
// 244.489 us; speedup vs baseline: 1.8240x; 1.8240x over previous
//
#include <hip/hip_runtime.h>
#include <cstdint>
#include <cstddef>

#define D_DIM 256
#define NT 64            // codes per sweep tile
#define SROWS 256        // rows per sweep block
#define SNS 4            // K splits in sweep (grid = 128*4 = 512)
#define MARGIN 1.3e-3f   // worst-case 2*eps bf16 bound (both-sided)
#define RCAP 2048        // resolve candidate list capacity per block

typedef unsigned int u32;
typedef unsigned short u16;
typedef unsigned long long u64;
typedef __attribute__((ext_vector_type(8))) short s16x8;
typedef __attribute__((ext_vector_type(4))) float f32x4;

static __device__ __forceinline__ u16 f2bf(float f) {
  u32 u = __float_as_uint(f);
  return (u16)((u + 0x7FFFu + ((u >> 16) & 1u)) >> 16);
}

// numpy pairwise_sum block for n=128 (bit-identical to rounds 6-11)
static __device__ __forceinline__ float np_pw128_sq(const float* __restrict__ p) {
  float r0, r1, r2, r3, r4, r5, r6, r7;
  {
    const float4 a = *reinterpret_cast<const float4*>(p);
    const float4 b = *reinterpret_cast<const float4*>(p + 4);
    r0 = __fmul_rn(a.x, a.x); r1 = __fmul_rn(a.y, a.y);
    r2 = __fmul_rn(a.z, a.z); r3 = __fmul_rn(a.w, a.w);
    r4 = __fmul_rn(b.x, b.x); r5 = __fmul_rn(b.y, b.y);
    r6 = __fmul_rn(b.z, b.z); r7 = __fmul_rn(b.w, b.w);
  }
  #pragma unroll
  for (int i = 8; i < 128; i += 8) {
    const float4 a = *reinterpret_cast<const float4*>(p + i);
    const float4 b = *reinterpret_cast<const float4*>(p + i + 4);
    r0 = __fadd_rn(r0, __fmul_rn(a.x, a.x));
    r1 = __fadd_rn(r1, __fmul_rn(a.y, a.y));
    r2 = __fadd_rn(r2, __fmul_rn(a.z, a.z));
    r3 = __fadd_rn(r3, __fmul_rn(a.w, a.w));
    r4 = __fadd_rn(r4, __fmul_rn(b.x, b.x));
    r5 = __fadd_rn(r5, __fmul_rn(b.y, b.y));
    r6 = __fadd_rn(r6, __fmul_rn(b.z, b.z));
    r7 = __fadd_rn(r7, __fmul_rn(b.w, b.w));
  }
  const float s01 = __fadd_rn(r0, r1);
  const float s23 = __fadd_rn(r2, r3);
  const float s45 = __fadd_rn(r4, r5);
  const float s67 = __fadd_rn(r6, r7);
  return __fadd_rn(__fadd_rn(s01, s23), __fadd_rn(s45, s67));
}

// exact r6-chain dot over one row pair (sequential-d fmaf, bit-identical)
static __device__ __forceinline__ float exact_dot256(
    const float* __restrict__ xp, const float* __restrict__ wp) {
  float a = 0.f;
  #pragma unroll 8
  for (int d4 = 0; d4 < 64; ++d4) {
    const float4 xv = *reinterpret_cast<const float4*>(xp + d4 * 4);
    const float4 wv = *reinterpret_cast<const float4*>(wp + d4 * 4);
    a = fmaf(xv.x, wv.x, a);
    a = fmaf(xv.y, wv.y, a);
    a = fmaf(xv.z, wv.z, a);
    a = fmaf(xv.w, wv.w, a);
  }
  return a;
}

// ---- K0: f32 -> bf16 stash (r10 verbatim) ----
__global__ __launch_bounds__(256) void cvt_kernel(
    const float* __restrict__ X, const float* __restrict__ W,
    u16* __restrict__ Xb, u16* __restrict__ Wb, int nx4, int nw4) {
  const int tid = blockIdx.x * blockDim.x + threadIdx.x;
  const int stride = gridDim.x * blockDim.x;
  for (int g = tid; g < nx4; g += stride) {
    const float4 v = reinterpret_cast<const float4*>(X)[g];
    ushort4 o; o.x = f2bf(v.x); o.y = f2bf(v.y); o.z = f2bf(v.z); o.w = f2bf(v.w);
    reinterpret_cast<ushort4*>(Xb)[g] = o;
  }
  for (int g = tid; g < nw4; g += stride) {
    const float4 v = reinterpret_cast<const float4*>(W)[g];
    ushort4 o; o.x = f2bf(v.x); o.y = f2bf(v.y); o.z = f2bf(v.z); o.w = f2bf(v.w);
    reinterpret_cast<ushort4*>(Wb)[g] = o;
  }
}

// 16-lane (DPP row) max-reduce of (v, idx), ties -> lower idx. VALU-only.
#define DPP_RED_STEP(CTRL)                                                     \
  {                                                                            \
    const float ov = __uint_as_float((u32)__builtin_amdgcn_update_dpp(         \
        0, (int)__float_as_uint(v), CTRL, 0xF, 0xF, true));                    \
    const int oi = __builtin_amdgcn_update_dpp(0, idx, CTRL, 0xF, 0xF, true);  \
    if (ov > v || (ov == v && oi < idx)) { v = ov; idx = oi; }                 \
  }

// ---- K1: MFMA sweep -> per-(row, 64-code-tile) top-1 (r11 verbatim) ----
__global__ __launch_bounds__(256, 2) void vq_sweep(
    const u16* __restrict__ Xb, const u16* __restrict__ Wb,
    float* __restrict__ tm, u16* __restrict__ ti, int K) {
  __shared__ u16 Ws[NT * D_DIM];  // 32 KB, [kc8][code][8] subtiled

  const int t = threadIdx.x;
  const int wv = t >> 6;
  const int lane = t & 63;
  const int l15 = lane & 15, lhi = lane >> 4;
  const int rb = blockIdx.x >> 2;      // SNS == 4
  const int hs = blockIdx.x & 3;
  const int row0 = rb * SROWS;
  const int wrow0 = row0 + wv * 64;
  const int c00 = hs * (K / SNS);      // 1024 codes per split

  s16x8 af[4][8];
  #pragma unroll
  for (int rt = 0; rt < 4; ++rt)
    #pragma unroll
    for (int kc = 0; kc < 8; ++kc)
      af[rt][kc] = *reinterpret_cast<const s16x8*>(
          Xb + (size_t)(wrow0 + rt * 16 + l15) * D_DIM + kc * 32 + lhi * 8);

  const int NTILES = K / SNS / NT;  // 16
  for (int ct = 0; ct < NTILES; ++ct) {
    __syncthreads();
    {  // stage W tile: codes c00+ct*64 .. +63
      const int code = t >> 2, k4 = t & 3;
      const u16* wp = Wb + (size_t)(c00 + ct * NT + code) * D_DIM;
      #pragma unroll
      for (int kk = 0; kk < 8; ++kk) {
        const int kc8 = kk * 4 + k4;
        *reinterpret_cast<uint4*>(&Ws[(kc8 * NT + code) * 8]) =
            *reinterpret_cast<const uint4*>(wp + kc8 * 8);
      }
    }
    __syncthreads();

    f32x4 acc[4][4];
    #pragma unroll
    for (int rt = 0; rt < 4; ++rt)
      #pragma unroll
      for (int c = 0; c < 4; ++c) acc[rt][c] = f32x4{0.f, 0.f, 0.f, 0.f};

    #pragma unroll
    for (int kc = 0; kc < 8; ++kc) {
      s16x8 bf[4];
      #pragma unroll
      for (int c = 0; c < 4; ++c)
        bf[c] = *reinterpret_cast<const s16x8*>(
            &Ws[((kc * 4 + lhi) * NT + c * 16 + l15) * 8]);
      #pragma unroll
      for (int c = 0; c < 4; ++c) {
        acc[0][c] = __builtin_amdgcn_mfma_f32_16x16x32_bf16(af[0][kc], bf[c], acc[0][c], 0, 0, 0);
        acc[1][c] = __builtin_amdgcn_mfma_f32_16x16x32_bf16(af[1][kc], bf[c], acc[1][c], 0, 0, 0);
        acc[2][c] = __builtin_amdgcn_mfma_f32_16x16x32_bf16(af[2][kc], bf[c], acc[2][c], 0, 0, 0);
        acc[3][c] = __builtin_amdgcn_mfma_f32_16x16x32_bf16(af[3][kc], bf[c], acc[3][c], 0, 0, 0);
      }
    }

    #pragma unroll
    for (int rt = 0; rt < 4; ++rt)
      #pragma unroll
      for (int r = 0; r < 4; ++r) {
        float v = acc[rt][0][r];
        int idx = c00 + ct * NT + l15;
        #pragma unroll
        for (int c = 1; c < 4; ++c) {
          const float vc = acc[rt][c][r];
          const int ic = c00 + ct * NT + c * 16 + l15;
          if (vc > v) { v = vc; idx = ic; }
        }
        DPP_RED_STEP(0x121)
        DPP_RED_STEP(0x122)
        DPP_RED_STEP(0x124)
        DPP_RED_STEP(0x128)
        if (l15 == 0) {
          const int row = wrow0 + rt * 16 + lhi * 4 + r;
          const int tile = hs * NTILES + ct;
          tm[(size_t)row * 64 + tile] = v;
          ti[(size_t)row * 64 + tile] = (u16)idx;
        }
      }
  }
}

// ---- K2: resolve, de-diverged: candidate list -> batch exact dots ----
// grid = N/128 = 256, block 256
__global__ __launch_bounds__(256) void vq_resolve(
    const float* __restrict__ X, const float* __restrict__ W,
    const float* __restrict__ tm, const u16* __restrict__ ti,
    float* __restrict__ outI, int K) {
  __shared__ float ftmp[256];
  __shared__ float xsqs[128];
  __shared__ u64 best64[128];
  __shared__ uint2 list[RCAP];
  __shared__ int cnt;

  const int t = threadIdx.x;
  const int row0 = blockIdx.x * 128;

  {  // per-row ||x||^2, numpy-pairwise-f32 exact
    const int r = t >> 1, half = t & 1;
    ftmp[t] = np_pw128_sq(X + (size_t)(row0 + r) * D_DIM + half * 128);
  }
  if (t == 0) cnt = 0;
  __syncthreads();
  if (t < 128) {
    xsqs[t] = __fadd_rn(ftmp[2 * t], ftmp[2 * t + 1]);
    best64[t] = 0xFFFFFFFFFFFFFFFFull;
  }
  __syncthreads();

  // Phase A (t<128, one row each): vectorized scan, push candidates
  if (t < 128) {
    const int row = row0 + t;
    const float4* tm4 = reinterpret_cast<const float4*>(tm + (size_t)row * 64);
    float4 q[16];
    float rowmax = -3.4e38f;
    #pragma unroll
    for (int i = 0; i < 16; ++i) {
      q[i] = tm4[i];
      rowmax = fmaxf(rowmax, fmaxf(fmaxf(q[i].x, q[i].y), fmaxf(q[i].z, q[i].w)));
    }
    const float thr = rowmax - MARGIN;
    const u16* tir = ti + (size_t)row * 64;
    #pragma unroll
    for (int i = 0; i < 16; ++i) {
      #pragma unroll
      for (int j = 0; j < 4; ++j) {
        const float v = (j == 0) ? q[i].x : (j == 1) ? q[i].y
                      : (j == 2) ? q[i].z : q[i].w;
        if (v >= thr) {
          const int code = (int)tir[i * 4 + j] & (K - 1);
          const int idx = atomicAdd(&cnt, 1);
          if (idx < RCAP) {
            uint2 e; e.x = (u32)t; e.y = (u32)code;
            list[idx] = e;
          } else {
            // overflow (~never): evaluate inline, still exact
            const float a = exact_dot256(X + (size_t)row * D_DIM,
                                         W + (size_t)code * D_DIM);
            const float dist = __fsub_rn(xsqs[t], 2.0f * a);
            const u64 packed = ((u64)__float_as_uint(dist) << 32) | (u32)code;
            atomicMin(&best64[t], packed);
          }
        }
      }
    }
  }
  __syncthreads();

  // Phase B: all 256 lanes evaluate candidates (no divergence)
  int n = cnt; if (n > RCAP) n = RCAP;
  for (int i = t; i < n; i += 256) {
    const uint2 e = list[i];
    const float a = exact_dot256(X + (size_t)(row0 + (int)e.x) * D_DIM,
                                 W + (size_t)e.y * D_DIM);
    const float dist = __fsub_rn(xsqs[e.x], 2.0f * a);   // ~256 > 0 always
    const u64 packed = ((u64)__float_as_uint(dist) << 32) | e.y;
    atomicMin(&best64[e.x], packed);    // lexicographic (dist, idx) min
  }
  __syncthreads();

  if (t < 128) outI[row0 + t] = (float)(u32)(best64[t] & 0xFFFFFFFFull);
}

// ---- K3: gather W[k], qst, commit partials (r10 verbatim) ----
__global__ __launch_bounds__(256) void vq_gather(
    const float* __restrict__ X, const float* __restrict__ W,
    const float* __restrict__ outI, float* __restrict__ outQ,
    double* __restrict__ partials, int K) {
  __shared__ double dsum[256];
  const int t = threadIdx.x;
  const int r = t >> 1, half = t & 1;
  const int row = blockIdx.x * 128 + r;
  const int ix = (int)outI[row];

  double csum = 0.0;
  {
    const int k = ix & (K - 1);
    const float* xp = X + (size_t)row * D_DIM + half * 128;
    const float* wp = W + (size_t)k * D_DIM + half * 128;
    float* op = outQ + (size_t)row * D_DIM + half * 128;
    #pragma unroll 4
    for (int i = 0; i < 128; i += 4) {
      const float4 xv = *reinterpret_cast<const float4*>(xp + i);
      const float4 wv = *reinterpret_cast<const float4*>(wp + i);
      const float d0 = __fsub_rn(wv.x, xv.x), d1 = __fsub_rn(wv.y, xv.y);
      const float d2 = __fsub_rn(wv.z, xv.z), d3 = __fsub_rn(wv.w, xv.w);
      csum += (double)d0 * d0 + (double)d1 * d1 + (double)d2 * d2 + (double)d3 * d3;
      float4 o;
      o.x = __fadd_rn(xv.x, d0);
      o.y = __fadd_rn(xv.y, d1);
      o.z = __fadd_rn(xv.z, d2);
      o.w = __fadd_rn(xv.w, d3);
      *reinterpret_cast<float4*>(op + i) = o;
    }
  }
  dsum[t] = csum;
  __syncthreads();
  for (int s = 128; s > 0; s >>= 1) {
    if (t < s) dsum[t] += dsum[t + s];
    __syncthreads();
  }
  if (t == 0) partials[blockIdx.x] = dsum[0];
}

// ---- K4: finalize scalars ----
__global__ __launch_bounds__(256) void vq_finalize(
    const double* __restrict__ partials, float* __restrict__ outS,
    double invCount) {
  __shared__ double dsum[256];
  const int t = threadIdx.x;
  dsum[t] = partials[t];
  __syncthreads();
  for (int s = 128; s > 0; s >>= 1) {
    if (t < s) dsum[t] += dsum[t + s];
    __syncthreads();
  }
  if (t == 0) {
    const float m = (float)(dsum[0] * invCount);
    outS[0] = __fadd_rn(m, __fmul_rn(0.25f, m));  // (1+BETA)*mean
    outS[1] = 0.f;
  }
}

// ---- host-anomaly beacons ----
__global__ void zero_out_kernel(float* __restrict__ out, int n) {
  const int i = blockIdx.x * blockDim.x + threadIdx.x;
  const int stride = gridDim.x * blockDim.x;
  for (int j = i; j < n; j += stride) out[j] = 0.f;
}
__global__ void beacon_kernel(float* __restrict__ out, float v) {
  if (threadIdx.x == 0) out[0] = v;
}

extern "C" void kernel_launch(void* const* d_in, const int* in_sizes, int n_in,
                              void* d_out, int out_size, void* d_ws, size_t ws_size,
                              hipStream_t stream) {
  float* outF = (float*)d_out;

  float hostBeacon = 0.f;
  if (n_in != 2) hostBeacon = 21.f;
  else if (in_sizes[0] != 32768 * 256) hostBeacon = 23.f;
  else if (in_sizes[1] != 4096 * 256) hostBeacon = 25.f;
  else if (ws_size < 4096) hostBeacon = 27.f;
  else if (out_size != 32768 * 256 + 32768 + 2) hostBeacon = 29.f;

  if (hostBeacon != 0.f) {
    zero_out_kernel<<<dim3(2048), dim3(256), 0, stream>>>(outF, out_size);
    beacon_kernel<<<dim3(1), dim3(64), 0, stream>>>(outF, hostBeacon);
    return;
  }

  const float* X = (const float*)d_in[0];   // f32 [32768, 256]
  const float* W = (const float*)d_in[1];   // f32 [4096, 256]
  const int N = 32768, K = 4096;

  double* partials = (double*)d_ws;          // 256 doubles = 2048 B
  float* outQ = outF;                        // [N*256]  (32 MiB)
  float* outI = outQ + (size_t)N * D_DIM;    // [N]
  float* outS = outI + N;                    // [2]

  // stash layout inside outQ (consumed by sweep/resolve, then overwritten by
  // vq_gather in later stream-ordered kernels):
  //   Xb bf16 [0,16Mi) | Wb bf16 [16Mi,18Mi) | tm f32 [18Mi,26Mi) | ti u16 [26Mi,30Mi)
  u16* Xb = (u16*)outQ;
  u16* Wb = (u16*)((char*)d_out + 16777216);
  float* tmv = (float*)((char*)d_out + 18874368);
  u16* tiv = (u16*)((char*)d_out + 27262976);

  cvt_kernel<<<dim3(2048), dim3(256), 0, stream>>>(
      X, W, Xb, Wb, N * D_DIM / 4, K * D_DIM / 4);
  vq_sweep<<<dim3((N / SROWS) * SNS), dim3(256), 0, stream>>>(Xb, Wb, tmv, tiv, K);
  vq_resolve<<<dim3(N / 128), dim3(256), 0, stream>>>(X, W, tmv, tiv, outI, K);
  vq_gather<<<dim3(N / 128), dim3(256), 0, stream>>>(X, W, outI, outQ, partials, K);
  vq_finalize<<<dim3(1), dim3(256), 0, stream>>>(partials, outS,
                                                 1.0 / ((double)N * D_DIM));
}

// Round 13
// 240.334 us; speedup vs baseline: 1.8555x; 1.0173x over previous
//
#include <hip/hip_runtime.h>
#include <cstdint>
#include <cstddef>

#define D_DIM 256
#define NT 64            // codes per sweep tile
#define SROWS 256        // rows per sweep block
#define SNS 4            // K splits in sweep (grid = 128*4 = 512)
#define MARGIN 1.3e-3f   // worst-case 2*eps bf16 bound (both-sided)
#define RCAP 2048        // resolve candidate list capacity per block

typedef unsigned int u32;
typedef unsigned short u16;
typedef unsigned long long u64;
typedef __attribute__((ext_vector_type(8))) short s16x8;
typedef __attribute__((ext_vector_type(4))) float f32x4;

static __device__ __forceinline__ u16 f2bf(float f) {
  u32 u = __float_as_uint(f);
  return (u16)((u + 0x7FFFu + ((u >> 16) & 1u)) >> 16);
}

// numpy pairwise_sum block for n=128 (bit-identical to rounds 6-12)
static __device__ __forceinline__ float np_pw128_sq(const float* __restrict__ p) {
  float r0, r1, r2, r3, r4, r5, r6, r7;
  {
    const float4 a = *reinterpret_cast<const float4*>(p);
    const float4 b = *reinterpret_cast<const float4*>(p + 4);
    r0 = __fmul_rn(a.x, a.x); r1 = __fmul_rn(a.y, a.y);
    r2 = __fmul_rn(a.z, a.z); r3 = __fmul_rn(a.w, a.w);
    r4 = __fmul_rn(b.x, b.x); r5 = __fmul_rn(b.y, b.y);
    r6 = __fmul_rn(b.z, b.z); r7 = __fmul_rn(b.w, b.w);
  }
  #pragma unroll
  for (int i = 8; i < 128; i += 8) {
    const float4 a = *reinterpret_cast<const float4*>(p + i);
    const float4 b = *reinterpret_cast<const float4*>(p + i + 4);
    r0 = __fadd_rn(r0, __fmul_rn(a.x, a.x));
    r1 = __fadd_rn(r1, __fmul_rn(a.y, a.y));
    r2 = __fadd_rn(r2, __fmul_rn(a.z, a.z));
    r3 = __fadd_rn(r3, __fmul_rn(a.w, a.w));
    r4 = __fadd_rn(r4, __fmul_rn(b.x, b.x));
    r5 = __fadd_rn(r5, __fmul_rn(b.y, b.y));
    r6 = __fadd_rn(r6, __fmul_rn(b.z, b.z));
    r7 = __fadd_rn(r7, __fmul_rn(b.w, b.w));
  }
  const float s01 = __fadd_rn(r0, r1);
  const float s23 = __fadd_rn(r2, r3);
  const float s45 = __fadd_rn(r4, r5);
  const float s67 = __fadd_rn(r6, r7);
  return __fadd_rn(__fadd_rn(s01, s23), __fadd_rn(s45, s67));
}

// exact r6-chain dot (sequential-d fmaf, bit-identical)
static __device__ __forceinline__ float exact_dot256(
    const float* __restrict__ xp, const float* __restrict__ wp) {
  float a = 0.f;
  #pragma unroll 8
  for (int d4 = 0; d4 < 64; ++d4) {
    const float4 xv = *reinterpret_cast<const float4*>(xp + d4 * 4);
    const float4 wv = *reinterpret_cast<const float4*>(wp + d4 * 4);
    a = fmaf(xv.x, wv.x, a);
    a = fmaf(xv.y, wv.y, a);
    a = fmaf(xv.z, wv.z, a);
    a = fmaf(xv.w, wv.w, a);
  }
  return a;
}

// ---- K0: f32 -> bf16 stash (r10 verbatim) ----
__global__ __launch_bounds__(256) void cvt_kernel(
    const float* __restrict__ X, const float* __restrict__ W,
    u16* __restrict__ Xb, u16* __restrict__ Wb, int nx4, int nw4) {
  const int tid = blockIdx.x * blockDim.x + threadIdx.x;
  const int stride = gridDim.x * blockDim.x;
  for (int g = tid; g < nx4; g += stride) {
    const float4 v = reinterpret_cast<const float4*>(X)[g];
    ushort4 o; o.x = f2bf(v.x); o.y = f2bf(v.y); o.z = f2bf(v.z); o.w = f2bf(v.w);
    reinterpret_cast<ushort4*>(Xb)[g] = o;
  }
  for (int g = tid; g < nw4; g += stride) {
    const float4 v = reinterpret_cast<const float4*>(W)[g];
    ushort4 o; o.x = f2bf(v.x); o.y = f2bf(v.y); o.z = f2bf(v.z); o.w = f2bf(v.w);
    reinterpret_cast<ushort4*>(Wb)[g] = o;
  }
}

// 16-lane (DPP row) max-reduce of (v, idx), ties -> lower idx. VALU-only.
#define DPP_RED_STEP(CTRL)                                                     \
  {                                                                            \
    const float ov = __uint_as_float((u32)__builtin_amdgcn_update_dpp(         \
        0, (int)__float_as_uint(v), CTRL, 0xF, 0xF, true));                    \
    const int oi = __builtin_amdgcn_update_dpp(0, idx, CTRL, 0xF, 0xF, true);  \
    if (ov > v || (ov == v && oi < idx)) { v = ov; idx = oi; }                 \
  }

// ---- K1: MFMA sweep -> per-(row, 64-code-tile) top-1, LDS-accumulated and
// written coalesced at block end (fixes 11x partial-line write amplification)
// grid = (N/SROWS)*SNS = 512, block 256 (4 waves x 64 rows, rt=4)
__global__ __launch_bounds__(256, 2) void vq_sweep(
    const u16* __restrict__ Xb, const u16* __restrict__ Wb,
    float* __restrict__ tm, u16* __restrict__ ti, int K) {
  __shared__ u16 Ws[NT * D_DIM];        // 32 KB, [kc8][code][8] subtiled
  __shared__ float tmS[SROWS][16];      // 16 KB per-tile top-1 values
  __shared__ u16 tiS[SROWS][16];        // 8 KB per-tile top-1 indices

  const int t = threadIdx.x;
  const int wv = t >> 6;
  const int lane = t & 63;
  const int l15 = lane & 15, lhi = lane >> 4;
  const int rb = blockIdx.x >> 2;      // SNS == 4
  const int hs = blockIdx.x & 3;
  const int row0 = rb * SROWS;
  const int wrow0 = row0 + wv * 64;
  const int c00 = hs * (K / SNS);      // 1024 codes per split

  s16x8 af[4][8];
  #pragma unroll
  for (int rt = 0; rt < 4; ++rt)
    #pragma unroll
    for (int kc = 0; kc < 8; ++kc)
      af[rt][kc] = *reinterpret_cast<const s16x8*>(
          Xb + (size_t)(wrow0 + rt * 16 + l15) * D_DIM + kc * 32 + lhi * 8);

  const int NTILES = K / SNS / NT;  // 16
  for (int ct = 0; ct < NTILES; ++ct) {
    __syncthreads();
    {  // stage W tile: codes c00+ct*64 .. +63
      const int code = t >> 2, k4 = t & 3;
      const u16* wp = Wb + (size_t)(c00 + ct * NT + code) * D_DIM;
      #pragma unroll
      for (int kk = 0; kk < 8; ++kk) {
        const int kc8 = kk * 4 + k4;
        *reinterpret_cast<uint4*>(&Ws[(kc8 * NT + code) * 8]) =
            *reinterpret_cast<const uint4*>(wp + kc8 * 8);
      }
    }
    __syncthreads();

    f32x4 acc[4][4];
    #pragma unroll
    for (int rt = 0; rt < 4; ++rt)
      #pragma unroll
      for (int c = 0; c < 4; ++c) acc[rt][c] = f32x4{0.f, 0.f, 0.f, 0.f};

    #pragma unroll
    for (int kc = 0; kc < 8; ++kc) {
      s16x8 bf[4];
      #pragma unroll
      for (int c = 0; c < 4; ++c)
        bf[c] = *reinterpret_cast<const s16x8*>(
            &Ws[((kc * 4 + lhi) * NT + c * 16 + l15) * 8]);
      #pragma unroll
      for (int c = 0; c < 4; ++c) {
        acc[0][c] = __builtin_amdgcn_mfma_f32_16x16x32_bf16(af[0][kc], bf[c], acc[0][c], 0, 0, 0);
        acc[1][c] = __builtin_amdgcn_mfma_f32_16x16x32_bf16(af[1][kc], bf[c], acc[1][c], 0, 0, 0);
        acc[2][c] = __builtin_amdgcn_mfma_f32_16x16x32_bf16(af[2][kc], bf[c], acc[2][c], 0, 0, 0);
        acc[3][c] = __builtin_amdgcn_mfma_f32_16x16x32_bf16(af[3][kc], bf[c], acc[3][c], 0, 0, 0);
      }
    }

    // per-row tile-top1 (value, idx) -> LDS (no global writes here)
    #pragma unroll
    for (int rt = 0; rt < 4; ++rt)
      #pragma unroll
      for (int r = 0; r < 4; ++r) {
        float v = acc[rt][0][r];
        int idx = c00 + ct * NT + l15;
        #pragma unroll
        for (int c = 1; c < 4; ++c) {
          const float vc = acc[rt][c][r];
          const int ic = c00 + ct * NT + c * 16 + l15;
          if (vc > v) { v = vc; idx = ic; }
        }
        DPP_RED_STEP(0x121)
        DPP_RED_STEP(0x122)
        DPP_RED_STEP(0x124)
        DPP_RED_STEP(0x128)
        if (l15 == 0) {
          const int lr = wv * 64 + rt * 16 + lhi * 4 + r;  // local row
          tmS[lr][ct] = v;
          tiS[lr][ct] = (u16)idx;
        }
      }
  }
  __syncthreads();

  // coalesced flush: per row, 16 f32 (64B) and 16 u16 (32B), aligned chunks
  #pragma unroll
  for (int i = 0; i < 4; ++i) {
    const int idx = i * 256 + t;
    const int lr = idx >> 2, part = idx & 3;
    const int row = row0 + lr;
    *reinterpret_cast<float4*>(&tm[(size_t)row * 64 + hs * 16 + part * 4]) =
        *reinterpret_cast<const float4*>(&tmS[lr][part * 4]);
  }
  #pragma unroll
  for (int i = 0; i < 4; ++i) {
    const int idx = i * 256 + t;
    const int lr = idx >> 2, part = idx & 3;
    const int row = row0 + lr;
    *reinterpret_cast<uint2*>(&ti[(size_t)row * 64 + hs * 16 + part * 4]) =
        *reinterpret_cast<const uint2*>(&tiS[lr][part * 4]);
  }
}

// ---- K2: resolve (r12 verbatim): candidate list -> batch exact dots ----
__global__ __launch_bounds__(256) void vq_resolve(
    const float* __restrict__ X, const float* __restrict__ W,
    const float* __restrict__ tm, const u16* __restrict__ ti,
    float* __restrict__ outI, int K) {
  __shared__ float ftmp[256];
  __shared__ float xsqs[128];
  __shared__ u64 best64[128];
  __shared__ uint2 list[RCAP];
  __shared__ int cnt;

  const int t = threadIdx.x;
  const int row0 = blockIdx.x * 128;

  {
    const int r = t >> 1, half = t & 1;
    ftmp[t] = np_pw128_sq(X + (size_t)(row0 + r) * D_DIM + half * 128);
  }
  if (t == 0) cnt = 0;
  __syncthreads();
  if (t < 128) {
    xsqs[t] = __fadd_rn(ftmp[2 * t], ftmp[2 * t + 1]);
    best64[t] = 0xFFFFFFFFFFFFFFFFull;
  }
  __syncthreads();

  if (t < 128) {
    const int row = row0 + t;
    const float4* tm4 = reinterpret_cast<const float4*>(tm + (size_t)row * 64);
    float4 q[16];
    float rowmax = -3.4e38f;
    #pragma unroll
    for (int i = 0; i < 16; ++i) {
      q[i] = tm4[i];
      rowmax = fmaxf(rowmax, fmaxf(fmaxf(q[i].x, q[i].y), fmaxf(q[i].z, q[i].w)));
    }
    const float thr = rowmax - MARGIN;
    const u16* tir = ti + (size_t)row * 64;
    #pragma unroll
    for (int i = 0; i < 16; ++i) {
      #pragma unroll
      for (int j = 0; j < 4; ++j) {
        const float v = (j == 0) ? q[i].x : (j == 1) ? q[i].y
                      : (j == 2) ? q[i].z : q[i].w;
        if (v >= thr) {
          const int code = (int)tir[i * 4 + j] & (K - 1);
          const int idx = atomicAdd(&cnt, 1);
          if (idx < RCAP) {
            uint2 e; e.x = (u32)t; e.y = (u32)code;
            list[idx] = e;
          } else {
            const float a = exact_dot256(X + (size_t)row * D_DIM,
                                         W + (size_t)code * D_DIM);
            const float dist = __fsub_rn(xsqs[t], 2.0f * a);
            const u64 packed = ((u64)__float_as_uint(dist) << 32) | (u32)code;
            atomicMin(&best64[t], packed);
          }
        }
      }
    }
  }
  __syncthreads();

  int n = cnt; if (n > RCAP) n = RCAP;
  for (int i = t; i < n; i += 256) {
    const uint2 e = list[i];
    const float a = exact_dot256(X + (size_t)(row0 + (int)e.x) * D_DIM,
                                 W + (size_t)e.y * D_DIM);
    const float dist = __fsub_rn(xsqs[e.x], 2.0f * a);
    const u64 packed = ((u64)__float_as_uint(dist) << 32) | e.y;
    atomicMin(&best64[e.x], packed);
  }
  __syncthreads();

  if (t < 128) outI[row0 + t] = (float)(u32)(best64[t] & 0xFFFFFFFFull);
}

// ---- K3: gather W[k], qst, commit partials (r10 verbatim) ----
__global__ __launch_bounds__(256) void vq_gather(
    const float* __restrict__ X, const float* __restrict__ W,
    const float* __restrict__ outI, float* __restrict__ outQ,
    double* __restrict__ partials, int K) {
  __shared__ double dsum[256];
  const int t = threadIdx.x;
  const int r = t >> 1, half = t & 1;
  const int row = blockIdx.x * 128 + r;
  const int ix = (int)outI[row];

  double csum = 0.0;
  {
    const int k = ix & (K - 1);
    const float* xp = X + (size_t)row * D_DIM + half * 128;
    const float* wp = W + (size_t)k * D_DIM + half * 128;
    float* op = outQ + (size_t)row * D_DIM + half * 128;
    #pragma unroll 4
    for (int i = 0; i < 128; i += 4) {
      const float4 xv = *reinterpret_cast<const float4*>(xp + i);
      const float4 wv = *reinterpret_cast<const float4*>(wp + i);
      const float d0 = __fsub_rn(wv.x, xv.x), d1 = __fsub_rn(wv.y, xv.y);
      const float d2 = __fsub_rn(wv.z, xv.z), d3 = __fsub_rn(wv.w, xv.w);
      csum += (double)d0 * d0 + (double)d1 * d1 + (double)d2 * d2 + (double)d3 * d3;
      float4 o;
      o.x = __fadd_rn(xv.x, d0);
      o.y = __fadd_rn(xv.y, d1);
      o.z = __fadd_rn(xv.z, d2);
      o.w = __fadd_rn(xv.w, d3);
      *reinterpret_cast<float4*>(op + i) = o;
    }
  }
  dsum[t] = csum;
  __syncthreads();
  for (int s = 128; s > 0; s >>= 1) {
    if (t < s) dsum[t] += dsum[t + s];
    __syncthreads();
  }
  if (t == 0) partials[blockIdx.x] = dsum[0];
}

// ---- K4: finalize scalars ----
__global__ __launch_bounds__(256) void vq_finalize(
    const double* __restrict__ partials, float* __restrict__ outS,
    double invCount) {
  __shared__ double dsum[256];
  const int t = threadIdx.x;
  dsum[t] = partials[t];
  __syncthreads();
  for (int s = 128; s > 0; s >>= 1) {
    if (t < s) dsum[t] += dsum[t + s];
    __syncthreads();
  }
  if (t == 0) {
    const float m = (float)(dsum[0] * invCount);
    outS[0] = __fadd_rn(m, __fmul_rn(0.25f, m));  // (1+BETA)*mean
    outS[1] = 0.f;
  }
}

// ---- host-anomaly beacons ----
__global__ void zero_out_kernel(float* __restrict__ out, int n) {
  const int i = blockIdx.x * blockDim.x + threadIdx.x;
  const int stride = gridDim.x * blockDim.x;
  for (int j = i; j < n; j += stride) out[j] = 0.f;
}
__global__ void beacon_kernel(float* __restrict__ out, float v) {
  if (threadIdx.x == 0) out[0] = v;
}

extern "C" void kernel_launch(void* const* d_in, const int* in_sizes, int n_in,
                              void* d_out, int out_size, void* d_ws, size_t ws_size,
                              hipStream_t stream) {
  float* outF = (float*)d_out;

  float hostBeacon = 0.f;
  if (n_in != 2) hostBeacon = 21.f;
  else if (in_sizes[0] != 32768 * 256) hostBeacon = 23.f;
  else if (in_sizes[1] != 4096 * 256) hostBeacon = 25.f;
  else if (ws_size < 4096) hostBeacon = 27.f;
  else if (out_size != 32768 * 256 + 32768 + 2) hostBeacon = 29.f;

  if (hostBeacon != 0.f) {
    zero_out_kernel<<<dim3(2048), dim3(256), 0, stream>>>(outF, out_size);
    beacon_kernel<<<dim3(1), dim3(64), 0, stream>>>(outF, hostBeacon);
    return;
  }

  const float* X = (const float*)d_in[0];   // f32 [32768, 256]
  const float* W = (const float*)d_in[1];   // f32 [4096, 256]
  const int N = 32768, K = 4096;

  double* partials = (double*)d_ws;          // 256 doubles = 2048 B
  float* outQ = outF;                        // [N*256]  (32 MiB)
  float* outI = outQ + (size_t)N * D_DIM;    // [N]
  float* outS = outI + N;                    // [2]

  // stash layout inside outQ (consumed by sweep/resolve, then overwritten by
  // vq_gather in later stream-ordered kernels):
  //   Xb bf16 [0,16Mi) | Wb bf16 [16Mi,18Mi) | tm f32 [18Mi,26Mi) | ti u16 [26Mi,30Mi)
  u16* Xb = (u16*)outQ;
  u16* Wb = (u16*)((char*)d_out + 16777216);
  float* tmv = (float*)((char*)d_out + 18874368);
  u16* tiv = (u16*)((char*)d_out + 27262976);

  cvt_kernel<<<dim3(2048), dim3(256), 0, stream>>>(
      X, W, Xb, Wb, N * D_DIM / 4, K * D_DIM / 4);
  vq_sweep<<<dim3((N / SROWS) * SNS), dim3(256), 0, stream>>>(Xb, Wb, tmv, tiv, K);
  vq_resolve<<<dim3(N / 128), dim3(256), 0, stream>>>(X, W, tmv, tiv, outI, K);
  vq_gather<<<dim3(N / 128), dim3(256), 0, stream>>>(X, W, outI, outQ, partials, K);
  vq_finalize<<<dim3(1), dim3(256), 0, stream>>>(partials, outS,
                                                 1.0 / ((double)N * D_DIM));
}